// Round 5
// baseline (1992.500 us; speedup 1.0000x reference)
//
#include <hip/hip_runtime.h>
#include <stdint.h>

#define TOKENS 8192
#define OUT_F  16384
#define IN_F   4096

typedef short bf16x8 __attribute__((ext_vector_type(8)));
typedef float f32x4  __attribute__((ext_vector_type(4)));

__device__ __forceinline__ unsigned short bf16_rne(float f) {
    union { float f; unsigned int u; } v; v.f = f;
    unsigned int u = v.u;
    u += 0x7fffu + ((u >> 16) & 1u);   // round-to-nearest-even (finite inputs)
    return (unsigned short)(u >> 16);
}

__device__ __forceinline__ unsigned int pack_bf16x2(float a, float b) {
    return (unsigned int)bf16_rne(a) | ((unsigned int)bf16_rne(b) << 16);
}

// async global->LDS DMA, 16B/lane. LDS dst is wave-uniform base + lane*16.
__device__ __forceinline__ void async_cp16(const void* gptr, void* ldsptr) {
    __builtin_amdgcn_global_load_lds(
        (const __attribute__((address_space(1))) unsigned int*)gptr,
        (__attribute__((address_space(3))) unsigned int*)ldsptr,
        16, 0, 0);
}

// ---------------- pre-pass 1: x fp32 -> bf16 ----------------
__global__ __launch_bounds__(256) void cvt_input_kernel(
    const float* __restrict__ in, unsigned short* __restrict__ out, int n8)
{
    int i = blockIdx.x * 256 + threadIdx.x;
    if (i >= n8) return;
    size_t base = (size_t)i * 8;
    float4 a = *(const float4*)(in + base);
    float4 b = *(const float4*)(in + base + 4);
    uint4 p;
    p.x = pack_bf16x2(a.x, a.y);  p.y = pack_bf16x2(a.z, a.w);
    p.z = pack_bf16x2(b.x, b.y);  p.w = pack_bf16x2(b.z, b.w);
    *(uint4*)(out + base) = p;
}

// ---------------- pre-pass 2: idx -> bf16(LUT[idx]) ----------------
__global__ __launch_bounds__(256) void dequant_kernel(
    const int* __restrict__ idx, const float* __restrict__ lut,
    unsigned short* __restrict__ out, int n8)
{
    __shared__ float slut[256];
    slut[threadIdx.x] = lut[threadIdx.x];
    __syncthreads();
    int i = blockIdx.x * 256 + threadIdx.x;
    if (i >= n8) return;
    size_t base = (size_t)i * 8;
    int4 i0 = *(const int4*)(idx + base);
    int4 i1 = *(const int4*)(idx + base + 4);
    uint4 p;
    p.x = pack_bf16x2(slut[i0.x], slut[i0.y]);
    p.y = pack_bf16x2(slut[i0.z], slut[i0.w]);
    p.z = pack_bf16x2(slut[i1.x], slut[i1.y]);
    p.w = pack_bf16x2(slut[i1.z], slut[i1.w]);
    *(uint4*)(out + base) = p;
}

// ======== 128x128 GEMM, 2 blocks/CU anti-phase, R2 deep-flight tile ========
// C[M,N] = A[M,K] * B[N,K]^T + bias.  BM=BN=128, BK=64, 4 waves (2M x 2N,
// wave-tile 64x64), 16x16x32 MFMA.  LDS 64 KiB = 2 buf x (A[128][64] +
// B[128][64]) bf16 -> 2 independent workgroups per CU (the overlap engine:
// each SIMD hosts 2 waves from DIFFERENT barrier groups, so one block's LDS
// drain runs under the other block's MFMA burst).
// Buffer byte map: buf0 A=0, B=16384; buf1 A=32768, B=49152.
// TILE (R2-verified rhythm, 2 barriers): read k0 -> stage B(t+1) -> read k1
// -> MFMA k0 -> lgkmcnt(0)+BAR (all RB reads drained -> RB.A writable) ->
// stage A(t+2) into RB -> MFMA k1 -> vmcnt(4)+BAR (per-thread DMA FIFO at
// gate: [A(t+1)x4, B(t+1)x4, A(t+2)x4] -> completes 8 oldest = tile t+1
// certified, leaves A(t+2) in flight).
// LDS swizzle (T2): phys = logical ^ (((logical>>7)&7)<<4) — involution on
// the 16B-chunk bits within each 128-B row; applied as pre-swizzled global
// SOURCE (linear global_load_lds dest) + XOR on ds_read column offset.
// Measured 0 bank conflicts (rounds 2/4; identical row width & pattern).
__global__ __launch_bounds__(256, 2) void palett_gemm128(
    const unsigned short* __restrict__ A,   // [TOKENS][IN_F] bf16
    const unsigned short* __restrict__ B,   // [OUT_F][IN_F] bf16
    const float* __restrict__ bias,
    float* __restrict__ out)
{
    __shared__ __align__(16) char sm[65536];

    const int t    = threadIdx.x;
    const int w    = t >> 6;       // wave 0..3
    const int l    = t & 63;
    const int quad = l >> 4;
    const int r16  = l & 15;
    const int wr   = w >> 1;       // wave M row (0..1) -> 64 rows
    const int wc   = w & 1;        // wave N col (0..1) -> 64 cols

    // T1: XCD-aware bijective block swizzle (nwg=8192, 8192%8==0)
    const int orig = blockIdx.y * gridDim.x + blockIdx.x;   // 0..8191
    const int swzb = (orig & 7) * 1024 + (orig >> 3);
    const int n0   = (swzb & 127) << 7;
    const int m0   = (swzb >> 7) << 7;

    // staging source (pre-swizzled): per DMA round r, wave w covers rows
    // [r*32 + w*8 + (l>>3)], 16B chunk at swizzled col ((l&7)^(l>>3))*8 elems.
    const int srow = w * 8 + (l >> 3);               // 0..31 (+32 per round)
    const int scol = ((l & 7) ^ (l >> 3)) << 3;      // elems
    const unsigned short* pA = A + (size_t)(m0 + srow) * IN_F + scol;
    const unsigned short* pB = B + (size_t)(n0 + srow) * IN_F + scol;

    // ds_read byte-offset components (XOR-swizzled chunk within 128-B row)
    const int cswz = (r16 & 7) << 4;
    int aRow[4], bRow[4];
#pragma unroll
    for (int i = 0; i < 4; ++i) {
        aRow[i] = (wr * 64 + i * 16 + r16) * 128;            // A row byte
        bRow[i] = 16384 + (wc * 64 + i * 16 + r16) * 128;    // B row byte
    }

    f32x4  acc[4][4] = {};
    bf16x8 fA[2][4], fB[2][4];

#define BAR()   asm volatile("s_barrier" ::: "memory")

// stage one 128x64 operand tile (16 KB): 4 DMA rounds x (256 thr x 16 B)
#define STAGE_A(LB, KOFF) do {                                                   \
    _Pragma("unroll")                                                            \
    for (int r_ = 0; r_ < 4; ++r_)                                               \
        async_cp16(pA + (size_t)(r_ * 32) * IN_F + (KOFF),                       \
                   sm + (LB) + r_ * 4096 + w * 1024);                            \
} while (0)

#define STAGE_B(LB, KOFF) do {                                                   \
    _Pragma("unroll")                                                            \
    for (int r_ = 0; r_ < 4; ++r_)                                               \
        async_cp16(pB + (size_t)(r_ * 32) * IN_F + (KOFF),                       \
                   sm + (LB) + 16384 + r_ * 4096 + w * 1024);                    \
} while (0)

// read all 8 fragments (A0-3, B0-3) of k-step KK into slot S_
#define READ_K(S_, RB_, KK_) do {                                                \
    _Pragma("unroll")                                                            \
    for (int i_ = 0; i_ < 4; ++i_)                                               \
        fA[S_][i_] = *(const bf16x8*)(sm + (RB_) + aRow[i_]                      \
                                      + ((((KK_) * 64) + quad * 16) ^ cswz));    \
    _Pragma("unroll")                                                            \
    for (int j_ = 0; j_ < 4; ++j_)                                               \
        fB[S_][j_] = *(const bf16x8*)(sm + (RB_) + bRow[j_]                      \
                                      + ((((KK_) * 64) + quad * 16) ^ cswz));    \
} while (0)

// 16-MFMA cluster for k-step slot S_
#define MFMA_K(S_) do {                                                          \
    __builtin_amdgcn_s_setprio(1);                                               \
    _Pragma("unroll")                                                            \
    for (int i_ = 0; i_ < 4; ++i_) {                                             \
        _Pragma("unroll")                                                        \
        for (int j_ = 0; j_ < 4; ++j_)                                           \
            acc[i_][j_] = __builtin_amdgcn_mfma_f32_16x16x32_bf16(               \
                fA[S_][i_], fB[S_][j_], acc[i_][j_], 0, 0, 0);                   \
    }                                                                            \
    __builtin_amdgcn_s_setprio(0);                                               \
} while (0)

// KB_ = elem k-offset of tile t+1 (B staging), KA_ = of tile t+2 (A staging)
#define TILE(RB_, WB_, KB_, KA_) do {                                            \
    READ_K(0, RB_, 0);                                                           \
    STAGE_B(WB_, KB_);                                                           \
    READ_K(1, RB_, 1);                                                           \
    MFMA_K(0);                          /* waits k0 reads via counted lgkm */    \
    asm volatile("s_waitcnt lgkmcnt(0)" ::: "memory");  /* k1 reads drained */   \
    BAR();   /* all waves' RB reads complete -> RB.A writable */                 \
    STAGE_A(RB_, KA_);                                                           \
    MFMA_K(1);                                                                   \
    asm volatile("s_waitcnt vmcnt(4)" ::: "memory");    /* tile t+1 landed */    \
    BAR();                                                                       \
} while (0)

    // prologue: A(0),B(0) -> buf0; A(1) -> buf1
    STAGE_A(0,     0);
    STAGE_B(0,     0);
    STAGE_A(32768, 64);
    asm volatile("s_waitcnt vmcnt(4)" ::: "memory");  // tile0 landed, A(1) in flight
    BAR();

#pragma unroll 1
    for (int it = 0; it < 32; ++it) {
        const int tt  = 2 * it;
        const int kB0 = ((tt + 1) & 63) * 64;   // B of tile tt+1
        const int kA0 = ((tt + 2) & 63) * 64;   // A of tile tt+2
        const int kB1 = ((tt + 2) & 63) * 64;   // B of tile tt+2
        const int kA1 = ((tt + 3) & 63) * 64;   // A of tile tt+3
        TILE(0,     32768, kB0, kA0);
        TILE(32768, 0,     kB1, kA1);
    }
    asm volatile("s_waitcnt vmcnt(0)" ::: "memory"); // drain dangling prefetch

#undef TILE
#undef MFMA_K
#undef READ_K
#undef STAGE_B
#undef STAGE_A
#undef BAR

    // epilogue: C/D layout row = quad*4 + v, col = r16  (round-2 verified)
    float bj[4];
#pragma unroll
    for (int j = 0; j < 4; ++j) bj[j] = bias[n0 + wc * 64 + j * 16 + r16];

#pragma unroll
    for (int mf = 0; mf < 4; ++mf) {
        const int mrow = m0 + wr * 64 + mf * 16 + quad * 4;
#pragma unroll
        for (int nf = 0; nf < 4; ++nf) {
            const int n = n0 + wc * 64 + nf * 16 + r16;
#pragma unroll
            for (int v = 0; v < 4; ++v)
                out[(size_t)(mrow + v) * OUT_F + n] = acc[mf][nf][v] + bj[nf];
        }
    }
}

// ---------------- fused fallback (only if workspace too small) ----------------
__global__ __launch_bounds__(256) void palett_gemm_fused(
    const float* __restrict__ Af,             // [M][K] fp32
    const int* __restrict__ Widx,             // [N][K] int32
    const float* __restrict__ lut,
    const float* __restrict__ bias,
    float* __restrict__ out)
{
    __shared__ __align__(16) unsigned short smA[128 * 32];
    __shared__ __align__(16) unsigned short smB[128 * 32];
    __shared__ float slut[256];

    const int t    = threadIdx.x;
    const int w    = t >> 6;
    const int l    = t & 63;
    const int quad = l >> 4;
    const int r16  = l & 15;
    const int wr   = w >> 1;
    const int wc   = w & 1;

    const int m0 = blockIdx.y * 128;
    const int n0 = blockIdx.x * 128;

    const int g0  = t * 8;
    const int row = g0 >> 5;
    const int col = g0 & 31;

    char* const smA_c = (char*)smA;
    char* const smB_c = (char*)smB;

    slut[t] = lut[t];
    __syncthreads();

    uint32_t aoff[4], boff[4];
#pragma unroll
    for (int i = 0; i < 4; ++i) {
        aoff[i] = (uint32_t)(((wr * 64 + i * 16 + r16) * 32 + quad * 8) * 2);
        boff[i] = (uint32_t)(((wc * 64 + i * 16 + r16) * 32 + quad * 8) * 2);
    }

    f32x4 acc[4][4] = {};

    const float* af0 = Af + (size_t)(m0 + row) * IN_F + col;
    const float* af1 = Af + (size_t)(m0 + row + 64) * IN_F + col;
    const int*   wi0 = Widx + (size_t)(n0 + row) * IN_F + col;
    const int*   wi1 = Widx + (size_t)(n0 + row + 64) * IN_F + col;

    for (int k0 = 0; k0 < IN_F; k0 += 32) {
        float4 x0 = *(const float4*)(af0 + k0);
        float4 x1 = *(const float4*)(af0 + k0 + 4);
        uint4 p;
        p.x = pack_bf16x2(x0.x, x0.y); p.y = pack_bf16x2(x0.z, x0.w);
        p.z = pack_bf16x2(x1.x, x1.y); p.w = pack_bf16x2(x1.z, x1.w);
        *(uint4*)(smA_c + t * 16) = p;
        x0 = *(const float4*)(af1 + k0);
        x1 = *(const float4*)(af1 + k0 + 4);
        p.x = pack_bf16x2(x0.x, x0.y); p.y = pack_bf16x2(x0.z, x0.w);
        p.z = pack_bf16x2(x1.x, x1.y); p.w = pack_bf16x2(x1.z, x1.w);
        *(uint4*)(smA_c + 4096 + t * 16) = p;

        int4 j0 = *(const int4*)(wi0 + k0);
        int4 j1 = *(const int4*)(wi0 + k0 + 4);
        p.x = pack_bf16x2(slut[j0.x], slut[j0.y]);
        p.y = pack_bf16x2(slut[j0.z], slut[j0.w]);
        p.z = pack_bf16x2(slut[j1.x], slut[j1.y]);
        p.w = pack_bf16x2(slut[j1.z], slut[j1.w]);
        *(uint4*)(smB_c + t * 16) = p;
        j0 = *(const int4*)(wi1 + k0);
        j1 = *(const int4*)(wi1 + k0 + 4);
        p.x = pack_bf16x2(slut[j0.x], slut[j0.y]);
        p.y = pack_bf16x2(slut[j0.z], slut[j0.w]);
        p.z = pack_bf16x2(slut[j1.x], slut[j1.y]);
        p.w = pack_bf16x2(slut[j1.z], slut[j1.w]);
        *(uint4*)(smB_c + 4096 + t * 16) = p;
        __syncthreads();

        bf16x8 afr[4], bfr[4];
#pragma unroll
        for (int i = 0; i < 4; ++i) afr[i] = *(const bf16x8*)(smA_c + aoff[i]);
#pragma unroll
        for (int j = 0; j < 4; ++j) bfr[j] = *(const bf16x8*)(smB_c + boff[j]);
#pragma unroll
        for (int i = 0; i < 4; ++i)
#pragma unroll
            for (int j = 0; j < 4; ++j)
                acc[i][j] = __builtin_amdgcn_mfma_f32_16x16x32_bf16(
                    afr[i], bfr[j], acc[i][j], 0, 0, 0);
        __syncthreads();
    }

    float bj[4];
#pragma unroll
    for (int j = 0; j < 4; ++j) bj[j] = bias[n0 + wc * 64 + j * 16 + r16];

#pragma unroll
    for (int i = 0; i < 4; ++i) {
        const int mbase = m0 + wr * 64 + i * 16 + quad * 4;
#pragma unroll
        for (int j = 0; j < 4; ++j) {
            const int n = n0 + wc * 64 + j * 16 + r16;
#pragma unroll
            for (int v = 0; v < 4; ++v) {
                out[(size_t)(mbase + v) * OUT_F + n] = acc[i][j][v] + bj[j];
            }
        }
    }
}

extern "C" void kernel_launch(void* const* d_in, const int* in_sizes, int n_in,
                              void* d_out, int out_size, void* d_ws, size_t ws_size,
                              hipStream_t stream) {
    const float* input = (const float*)d_in[0];   // [8192][4096] fp32
    const int*   widx  = (const int*)d_in[1];     // [16384][4096] int32
    const float* lut   = (const float*)d_in[2];   // [256] fp32
    const float* bias  = (const float*)d_in[3];   // [16384] fp32
    float* out = (float*)d_out;                   // [8192][16384] fp32

    const size_t aBytes = (size_t)TOKENS * IN_F * sizeof(unsigned short); //  64 MB
    const size_t bBytes = (size_t)OUT_F  * IN_F * sizeof(unsigned short); // 128 MB

    if (ws_size >= aBytes + bBytes) {
        unsigned short* wsA = (unsigned short*)d_ws;
        unsigned short* wsB = (unsigned short*)((char*)d_ws + aBytes);
        const int nA8 = (TOKENS * IN_F) / 8;
        const int nB8 = (OUT_F  * IN_F) / 8;
        cvt_input_kernel<<<(nA8 + 255) / 256, 256, 0, stream>>>(input, wsA, nA8);
        dequant_kernel<<<(nB8 + 255) / 256, 256, 0, stream>>>(widx, lut, wsB, nB8);
        dim3 grid2(OUT_F / 128, TOKENS / 128);    // (128, 64) = 8192 blocks
        palett_gemm128<<<grid2, 256, 0, stream>>>(wsA, wsB, bias, out);
    } else {
        dim3 grid(OUT_F / 128, TOKENS / 128);
        palett_gemm_fused<<<grid, 256, 0, stream>>>(input, widx, lut, bias, out);
    }
}

// Round 6
// 1682.171 us; speedup vs baseline: 1.1845x; 1.1845x over previous
//
#include <hip/hip_runtime.h>
#include <stdint.h>

#define TOKENS 8192
#define OUT_F  16384
#define IN_F   4096

typedef short bf16x8 __attribute__((ext_vector_type(8)));
typedef float f32x4  __attribute__((ext_vector_type(4)));

__device__ __forceinline__ unsigned short bf16_rne(float f) {
    union { float f; unsigned int u; } v; v.f = f;
    unsigned int u = v.u;
    u += 0x7fffu + ((u >> 16) & 1u);   // round-to-nearest-even (finite inputs)
    return (unsigned short)(u >> 16);
}

__device__ __forceinline__ unsigned int pack_bf16x2(float a, float b) {
    return (unsigned int)bf16_rne(a) | ((unsigned int)bf16_rne(b) << 16);
}

// async global->LDS DMA, 16B/lane. LDS dst is wave-uniform base + lane*16.
__device__ __forceinline__ void async_cp16(const void* gptr, void* ldsptr) {
    __builtin_amdgcn_global_load_lds(
        (const __attribute__((address_space(1))) unsigned int*)gptr,
        (__attribute__((address_space(3))) unsigned int*)ldsptr,
        16, 0, 0);
}

// ---------------- pre-pass 1: x fp32 -> bf16 ----------------
__global__ __launch_bounds__(256) void cvt_input_kernel(
    const float* __restrict__ in, unsigned short* __restrict__ out, int n8)
{
    int i = blockIdx.x * 256 + threadIdx.x;
    if (i >= n8) return;
    size_t base = (size_t)i * 8;
    float4 a = *(const float4*)(in + base);
    float4 b = *(const float4*)(in + base + 4);
    uint4 p;
    p.x = pack_bf16x2(a.x, a.y);  p.y = pack_bf16x2(a.z, a.w);
    p.z = pack_bf16x2(b.x, b.y);  p.w = pack_bf16x2(b.z, b.w);
    *(uint4*)(out + base) = p;
}

// ---------------- pre-pass 2: idx -> bf16(LUT[idx]) ----------------
__global__ __launch_bounds__(256) void dequant_kernel(
    const int* __restrict__ idx, const float* __restrict__ lut,
    unsigned short* __restrict__ out, int n8)
{
    __shared__ float slut[256];
    slut[threadIdx.x] = lut[threadIdx.x];
    __syncthreads();
    int i = blockIdx.x * 256 + threadIdx.x;
    if (i >= n8) return;
    size_t base = (size_t)i * 8;
    int4 i0 = *(const int4*)(idx + base);
    int4 i1 = *(const int4*)(idx + base + 4);
    uint4 p;
    p.x = pack_bf16x2(slut[i0.x], slut[i0.y]);
    p.y = pack_bf16x2(slut[i0.z], slut[i0.w]);
    p.z = pack_bf16x2(slut[i1.x], slut[i1.y]);
    p.w = pack_bf16x2(slut[i1.z], slut[i1.w]);
    *(uint4*)(out + base) = p;
}

// ======== 256x256 GEMM, 4-phase deep-flight (round-2 best: 970us) ========
// C[M,N] = A[M,K] * B[N,K]^T + bias.  BM=BN=256, BK=64, 8 waves (2M x 4N),
// 16x16x32 MFMA, LDS 128 KiB = 2 buffers x (A[2x128x64] + B[2x128x64]) bf16.
// Buffer byte map: A0=0, A1=16384, B0=32768, B1=49152.  buf1 base = 65536.
// ONLY change vs round-2 bench: the block swizzle (L2-residency column order).
//
// Block swizzle: XCD c = orig&7 owns n-tiles [c*8, c*8+8); within the XCD,
// blocks run M-FASTEST down one n-tile column.  The 32 concurrently-resident
// blocks on an XCD (32 CUs x 1 block) share one 2 MB B panel -> L2-resident;
// A (64 MB) is streamed chip-wide in-phase through L3.  Cuts L3->L2 traffic
// ~2x and HBM fetch to near-compulsory vs the n-fastest raster.
__global__ __launch_bounds__(512, 2) void palett_gemm256(
    const unsigned short* __restrict__ A,   // [TOKENS][IN_F] bf16
    const unsigned short* __restrict__ B,   // [OUT_F][IN_F] bf16
    const float* __restrict__ bias,
    float* __restrict__ out)
{
    __shared__ __align__(16) char sm[131072];

    const int t    = threadIdx.x;
    const int w    = t >> 6;       // wave 0..7
    const int l    = t & 63;
    const int quad = l >> 4;
    const int r16  = l & 15;
    const int wr   = w >> 2;       // wave M row   (0..1) -> 128 rows
    const int wc   = w & 3;        // wave N col   (0..3) -> 64 cols

    // L2-residency column swizzle (bijective; nwg=2048, 2048%8==0)
    const int orig = blockIdx.y * gridDim.x + blockIdx.x;   // 0..2047
    const int c    = orig & 7;          // XCD chunk
    const int i    = orig >> 3;         // 0..255 within chunk
    const int nt   = c * 8 + (i >> 5);  // n-tile 0..63 (8 per XCD)
    const int mt   = i & 31;            // m-tile 0..31 (m-fastest in column)
    const int n0   = nt << 8;
    const int m0   = mt << 8;

    // staging source (pre-swizzled): lane covers row srow (+8 for 2nd load),
    // 16B chunk at swizzled column ((l&7)^(l>>3))*8 elems.
    const int srow = w * 16 + (l >> 3);              // 0..127 within half
    const int scol = ((l & 7) ^ (l >> 3)) << 3;      // elems
    const unsigned short* pA = A + (size_t)(m0 + srow) * IN_F + scol;
    const unsigned short* pB = B + (size_t)(n0 + srow) * IN_F + scol;

    // ds_read byte-offset components (XOR-swizzled columns) — 0-conflict verified
    const int cswz  = (r16 & 7) << 4;
    const int col0  = (quad * 16) ^ cswz;            // kk=0
    const int col1  = (64 + quad * 16) ^ cswz;       // kk=1
    const int arow  = r16 * 128;
    const int abase = wr * 16384;                            // this wave's A half
    const int bbase = 32768 + (wc >> 1) * 16384 + (wc & 1) * 8192; // B half + sub

    f32x4  acc[8][4] = {};
    bf16x8 rA[4][2], rB0[2][2], rB1[2][2];

#define BARRIER() asm volatile("s_barrier" ::: "memory")

#define STAGE(P, HOFF, LOFF, KOFF) do {                                          \
    async_cp16((P) + (size_t)(HOFF) * IN_F + (KOFF), sm + (LOFF) + w * 2048);    \
    async_cp16((P) + (size_t)((HOFF) + 8) * IN_F + (KOFF),                       \
               sm + (LOFF) + w * 2048 + 1024);                                   \
} while (0)

#define READ_A(RB_, MH) do {                                                     \
    _Pragma("unroll")                                                            \
    for (int i_ = 0; i_ < 4; ++i_) {                                             \
        rA[i_][0] = *(const bf16x8*)(sm + (RB_) + abase + ((MH)*4 + i_)*2048 + arow + col0); \
        rA[i_][1] = *(const bf16x8*)(sm + (RB_) + abase + ((MH)*4 + i_)*2048 + arow + col1); \
    }                                                                            \
} while (0)

#define READ_B(DST, RB_, NH) do {                                                \
    _Pragma("unroll")                                                            \
    for (int j_ = 0; j_ < 2; ++j_) {                                             \
        DST[j_][0] = *(const bf16x8*)(sm + (RB_) + bbase + ((NH)*2 + j_)*2048 + arow + col0); \
        DST[j_][1] = *(const bf16x8*)(sm + (RB_) + bbase + ((NH)*2 + j_)*2048 + arow + col1); \
    }                                                                            \
} while (0)

#define MFMA_Q(MH, NH, RB) do {                                                  \
    _Pragma("unroll")                                                            \
    for (int i_ = 0; i_ < 4; ++i_) {                                             \
        _Pragma("unroll")                                                        \
        for (int j_ = 0; j_ < 2; ++j_) {                                         \
            acc[(MH)*4+i_][(NH)*2+j_] = __builtin_amdgcn_mfma_f32_16x16x32_bf16( \
                rA[i_][0], RB[j_][0], acc[(MH)*4+i_][(NH)*2+j_], 0, 0, 0);       \
            acc[(MH)*4+i_][(NH)*2+j_] = __builtin_amdgcn_mfma_f32_16x16x32_bf16( \
                rA[i_][1], RB[j_][1], acc[(MH)*4+i_][(NH)*2+j_], 0, 0, 0);       \
        }                                                                        \
    }                                                                            \
} while (0)

// KB_ = element k-offset of tile t+1 (B staging), KA_ = k-offset of tile t+2 (A staging)
#define TILE(RB_, WB_, KB_, KA_) do {                                            \
    /* P1: stage B(t+1); read A-lo,B0; Q00 */                                    \
    STAGE(pB, 0,   (WB_) + 32768, KB_);                                          \
    STAGE(pB, 128, (WB_) + 49152, KB_);                                          \
    READ_A(RB_, 0);                                                              \
    READ_B(rB0, RB_, 0);                                                         \
    __builtin_amdgcn_s_setprio(1);                                               \
    MFMA_Q(0, 0, rB0);                                                           \
    __builtin_amdgcn_s_setprio(0);                                               \
    BARRIER();                                                                   \
    /* P2: read B1; Q01; read A-hi; drain lgkm (R fully read by this wave) */    \
    READ_B(rB1, RB_, 1);                                                         \
    __builtin_amdgcn_s_setprio(1);                                               \
    MFMA_Q(0, 1, rB1);                                                           \
    __builtin_amdgcn_s_setprio(0);                                               \
    READ_A(RB_, 1);                                                              \
    asm volatile("s_waitcnt lgkmcnt(0)" ::: "memory");                           \
    BARRIER();   /* all waves' reads from RB_ complete -> RB_ writable */        \
    /* P3: stage A(t+2) into RB_; Q10 */                                         \
    STAGE(pA, 0,   (RB_) + 0,     KA_);                                          \
    STAGE(pA, 128, (RB_) + 16384, KA_);                                          \
    __builtin_amdgcn_s_setprio(1);                                               \
    MFMA_Q(1, 0, rB0);                                                           \
    __builtin_amdgcn_s_setprio(0);                                               \
    BARRIER();                                                                   \
    /* P4: Q11; gate (leaves only A(t+2) in flight); certify tile t+1 */         \
    __builtin_amdgcn_s_setprio(1);                                               \
    MFMA_Q(1, 1, rB1);                                                           \
    __builtin_amdgcn_s_setprio(0);                                               \
    asm volatile("s_waitcnt vmcnt(4)" ::: "memory");                             \
    BARRIER();                                                                   \
} while (0)

    // prologue: tile0 (all 4 half-tiles) + A half-tiles of tile1 ("P3(-1)")
    STAGE(pA, 0,   0,             0);    // A-lo(0) -> buf0
    STAGE(pA, 128, 16384,         0);    // A-hi(0)
    STAGE(pB, 0,   32768,         0);    // B-lo(0)
    STAGE(pB, 128, 49152,         0);    // B-hi(0)
    STAGE(pA, 0,   65536 + 0,     64);   // A-lo(1) -> buf1
    STAGE(pA, 128, 65536 + 16384, 64);   // A-hi(1)
    asm volatile("s_waitcnt vmcnt(4)" ::: "memory");  // tile0 landed, A(1) in flight
    BARRIER();

#pragma unroll 1
    for (int it = 0; it < 32; ++it) {
        const int tt = 2 * it;
        const int kB0 = ((tt + 1) & 63) * 64;   // B of tile tt+1
        const int kA0 = ((tt + 2) & 63) * 64;   // A of tile tt+2
        const int kB1 = ((tt + 2) & 63) * 64;   // B of tile tt+2
        const int kA1 = ((tt + 3) & 63) * 64;   // A of tile tt+3
        TILE(0,     65536, kB0, kA0);
        TILE(65536, 0,     kB1, kA1);
    }
    asm volatile("s_waitcnt vmcnt(0)" ::: "memory"); // drain dangling prefetch

#undef TILE
#undef MFMA_Q
#undef READ_B
#undef READ_A
#undef STAGE
#undef BARRIER

    // epilogue: C/D layout row = quad*4 + v, col = r16
    float bj[4];
#pragma unroll
    for (int j = 0; j < 4; ++j) bj[j] = bias[n0 + wc * 64 + j * 16 + r16];

#pragma unroll
    for (int mf = 0; mf < 8; ++mf) {
        const int mrow = m0 + wr * 128 + mf * 16 + quad * 4;
#pragma unroll
        for (int nf = 0; nf < 4; ++nf) {
            const int n = n0 + wc * 64 + nf * 16 + r16;
#pragma unroll
            for (int v = 0; v < 4; ++v)
                out[(size_t)(mrow + v) * OUT_F + n] = acc[mf][nf][v] + bj[nf];
        }
    }
}

// ---------------- fused fallback (only if workspace too small) ----------------
__global__ __launch_bounds__(256) void palett_gemm_fused(
    const float* __restrict__ Af,             // [M][K] fp32
    const int* __restrict__ Widx,             // [N][K] int32
    const float* __restrict__ lut,
    const float* __restrict__ bias,
    float* __restrict__ out)
{
    __shared__ __align__(16) unsigned short smA[128 * 32];
    __shared__ __align__(16) unsigned short smB[128 * 32];
    __shared__ float slut[256];

    const int t    = threadIdx.x;
    const int w    = t >> 6;
    const int l    = t & 63;
    const int quad = l >> 4;
    const int r16  = l & 15;
    const int wr   = w >> 1;
    const int wc   = w & 1;

    const int m0 = blockIdx.y * 128;
    const int n0 = blockIdx.x * 128;

    const int g0  = t * 8;
    const int row = g0 >> 5;
    const int col = g0 & 31;

    char* const smA_c = (char*)smA;
    char* const smB_c = (char*)smB;

    slut[t] = lut[t];
    __syncthreads();

    uint32_t aoff[4], boff[4];
#pragma unroll
    for (int i = 0; i < 4; ++i) {
        aoff[i] = (uint32_t)(((wr * 64 + i * 16 + r16) * 32 + quad * 8) * 2);
        boff[i] = (uint32_t)(((wc * 64 + i * 16 + r16) * 32 + quad * 8) * 2);
    }

    f32x4 acc[4][4] = {};

    const float* af0 = Af + (size_t)(m0 + row) * IN_F + col;
    const float* af1 = Af + (size_t)(m0 + row + 64) * IN_F + col;
    const int*   wi0 = Widx + (size_t)(n0 + row) * IN_F + col;
    const int*   wi1 = Widx + (size_t)(n0 + row + 64) * IN_F + col;

    for (int k0 = 0; k0 < IN_F; k0 += 32) {
        float4 x0 = *(const float4*)(af0 + k0);
        float4 x1 = *(const float4*)(af0 + k0 + 4);
        uint4 p;
        p.x = pack_bf16x2(x0.x, x0.y); p.y = pack_bf16x2(x0.z, x0.w);
        p.z = pack_bf16x2(x1.x, x1.y); p.w = pack_bf16x2(x1.z, x1.w);
        *(uint4*)(smA_c + t * 16) = p;
        x0 = *(const float4*)(af1 + k0);
        x1 = *(const float4*)(af1 + k0 + 4);
        p.x = pack_bf16x2(x0.x, x0.y); p.y = pack_bf16x2(x0.z, x0.w);
        p.z = pack_bf16x2(x1.x, x1.y); p.w = pack_bf16x2(x1.z, x1.w);
        *(uint4*)(smA_c + 4096 + t * 16) = p;

        int4 j0 = *(const int4*)(wi0 + k0);
        int4 j1 = *(const int4*)(wi0 + k0 + 4);
        p.x = pack_bf16x2(slut[j0.x], slut[j0.y]);
        p.y = pack_bf16x2(slut[j0.z], slut[j0.w]);
        p.z = pack_bf16x2(slut[j1.x], slut[j1.y]);
        p.w = pack_bf16x2(slut[j1.z], slut[j1.w]);
        *(uint4*)(smB_c + t * 16) = p;
        j0 = *(const int4*)(wi1 + k0);
        j1 = *(const int4*)(wi1 + k0 + 4);
        p.x = pack_bf16x2(slut[j0.x], slut[j0.y]);
        p.y = pack_bf16x2(slut[j0.z], slut[j0.w]);
        p.z = pack_bf16x2(slut[j1.x], slut[j1.y]);
        p.w = pack_bf16x2(slut[j1.z], slut[j1.w]);
        *(uint4*)(smB_c + 4096 + t * 16) = p;
        __syncthreads();

        bf16x8 afr[4], bfr[4];
#pragma unroll
        for (int i = 0; i < 4; ++i) afr[i] = *(const bf16x8*)(smA_c + aoff[i]);
#pragma unroll
        for (int j = 0; j < 4; ++j) bfr[j] = *(const bf16x8*)(smB_c + boff[j]);
#pragma unroll
        for (int i = 0; i < 4; ++i)
#pragma unroll
            for (int j = 0; j < 4; ++j)
                acc[i][j] = __builtin_amdgcn_mfma_f32_16x16x32_bf16(
                    afr[i], bfr[j], acc[i][j], 0, 0, 0);
        __syncthreads();
    }

    float bj[4];
#pragma unroll
    for (int j = 0; j < 4; ++j) bj[j] = bias[n0 + wc * 64 + j * 16 + r16];

#pragma unroll
    for (int i = 0; i < 4; ++i) {
        const int mbase = m0 + wr * 64 + i * 16 + quad * 4;
#pragma unroll
        for (int j = 0; j < 4; ++j) {
            const int n = n0 + wc * 64 + j * 16 + r16;
#pragma unroll
            for (int v = 0; v < 4; ++v) {
                out[(size_t)(mbase + v) * OUT_F + n] = acc[i][j][v] + bj[j];
            }
        }
    }
}

extern "C" void kernel_launch(void* const* d_in, const int* in_sizes, int n_in,
                              void* d_out, int out_size, void* d_ws, size_t ws_size,
                              hipStream_t stream) {
    const float* input = (const float*)d_in[0];   // [8192][4096] fp32
    const int*   widx  = (const int*)d_in[1];     // [16384][4096] int32
    const float* lut   = (const float*)d_in[2];   // [256] fp32
    const float* bias  = (const float*)d_in[3];   // [16384] fp32
    float* out = (float*)d_out;                   // [8192][16384] fp32

    const size_t aBytes = (size_t)TOKENS * IN_F * sizeof(unsigned short); //  64 MB
    const size_t bBytes = (size_t)OUT_F  * IN_F * sizeof(unsigned short); // 128 MB

    if (ws_size >= aBytes + bBytes) {
        unsigned short* wsA = (unsigned short*)d_ws;
        unsigned short* wsB = (unsigned short*)((char*)d_ws + aBytes);
        const int nA8 = (TOKENS * IN_F) / 8;
        const int nB8 = (OUT_F  * IN_F) / 8;
        cvt_input_kernel<<<(nA8 + 255) / 256, 256, 0, stream>>>(input, wsA, nA8);
        dequant_kernel<<<(nB8 + 255) / 256, 256, 0, stream>>>(widx, lut, wsB, nB8);
        dim3 grid2(OUT_F / 256, TOKENS / 256);    // (64, 32) = 2048 blocks
        palett_gemm256<<<grid2, 512, 0, stream>>>(wsA, wsB, bias, out);
    } else {
        dim3 grid(OUT_F / 128, TOKENS / 128);
        palett_gemm_fused<<<grid, 256, 0, stream>>>(input, widx, lut, bias, out);
    }
}

// Round 7
// 1614.606 us; speedup vs baseline: 1.2340x; 1.0418x over previous
//
#include <hip/hip_runtime.h>
#include <stdint.h>

#define TOKENS 8192
#define OUT_F  16384
#define IN_F   4096

typedef short bf16x8 __attribute__((ext_vector_type(8)));
typedef float f32x4  __attribute__((ext_vector_type(4)));

__device__ __forceinline__ unsigned short bf16_rne(float f) {
    union { float f; unsigned int u; } v; v.f = f;
    unsigned int u = v.u;
    u += 0x7fffu + ((u >> 16) & 1u);   // round-to-nearest-even (finite inputs)
    return (unsigned short)(u >> 16);
}

__device__ __forceinline__ unsigned int pack_bf16x2(float a, float b) {
    return (unsigned int)bf16_rne(a) | ((unsigned int)bf16_rne(b) << 16);
}

// async global->LDS DMA, 16B/lane. LDS dst is wave-uniform base + lane*16.
__device__ __forceinline__ void async_cp16(const void* gptr, void* ldsptr) {
    __builtin_amdgcn_global_load_lds(
        (const __attribute__((address_space(1))) unsigned int*)gptr,
        (__attribute__((address_space(3))) unsigned int*)ldsptr,
        16, 0, 0);
}

// ---------------- pre-pass 1: x fp32 -> bf16 ----------------
__global__ __launch_bounds__(256) void cvt_input_kernel(
    const float* __restrict__ in, unsigned short* __restrict__ out, int n8)
{
    int i = blockIdx.x * 256 + threadIdx.x;
    if (i >= n8) return;
    size_t base = (size_t)i * 8;
    float4 a = *(const float4*)(in + base);
    float4 b = *(const float4*)(in + base + 4);
    uint4 p;
    p.x = pack_bf16x2(a.x, a.y);  p.y = pack_bf16x2(a.z, a.w);
    p.z = pack_bf16x2(b.x, b.y);  p.w = pack_bf16x2(b.z, b.w);
    *(uint4*)(out + base) = p;
}

// ---------------- pre-pass 2: idx -> bf16(LUT[idx]) ----------------
// Bank-replicated LUT: 32 copies, layout slut[entry*32 + copy].  Lane l reads
// copy (l&31) -> word address = entry*32 + (l&31) == (l&31) mod 32 -> bank is
// ALWAYS l&31 regardless of the random entry: 2 lanes/bank, conflict-free
// (m136: 2-way aliasing is free).  16 outputs/thread; all 4 int4 loads issued
// before any gather (ILP, no dependent-chain serialization).
__global__ __launch_bounds__(256) void dequant_kernel(
    const int* __restrict__ idx, const float* __restrict__ lut,
    unsigned short* __restrict__ out, int n16)
{
    __shared__ float slut[256 * 32];   // 32 KB

    const int t  = threadIdx.x;
    const int l  = t & 63;
    const int wv = t >> 6;             // wave 0..3 owns entries [64*wv, 64*wv+64)
    const int c  = l & 31;             // this lane's private bank/copy
    const int p  = l >> 5;             // half-wave

    // conflict-free replicated init: lane l holds lut[64*wv + l]; shuffle the
    // half-wave's 32 values through and write entry-major stride-32 (bank = c).
    {
        float v = lut[wv * 64 + l];
#pragma unroll
        for (int k = 0; k < 32; ++k) {
            float s = __shfl(v, p * 32 + k, 64);
            slut[(wv * 64 + p * 32 + k) * 32 + c] = s;
        }
    }
    __syncthreads();

#define LUTG(I_) slut[(I_) * 32 + c]

    int i = blockIdx.x * 256 + t;
    if (i >= n16) return;
    size_t base = (size_t)i * 16;
    // issue all loads first
    int4 a0 = *(const int4*)(idx + base);
    int4 a1 = *(const int4*)(idx + base + 4);
    int4 a2 = *(const int4*)(idx + base + 8);
    int4 a3 = *(const int4*)(idx + base + 12);
    uint4 p0, p1;
    p0.x = pack_bf16x2(LUTG(a0.x), LUTG(a0.y));
    p0.y = pack_bf16x2(LUTG(a0.z), LUTG(a0.w));
    p0.z = pack_bf16x2(LUTG(a1.x), LUTG(a1.y));
    p0.w = pack_bf16x2(LUTG(a1.z), LUTG(a1.w));
    p1.x = pack_bf16x2(LUTG(a2.x), LUTG(a2.y));
    p1.y = pack_bf16x2(LUTG(a2.z), LUTG(a2.w));
    p1.z = pack_bf16x2(LUTG(a3.x), LUTG(a3.y));
    p1.w = pack_bf16x2(LUTG(a3.z), LUTG(a3.w));
    *(uint4*)(out + base)     = p0;
    *(uint4*)(out + base + 8) = p1;
#undef LUTG
}

// ======== 256x256 GEMM, 4-phase deep-flight (round-2 bench: 970us) ========
// C[M,N] = A[M,K] * B[N,K]^T + bias.  BM=BN=256, BK=64, 8 waves (2M x 4N),
// 16x16x32 MFMA, LDS 128 KiB = 2 buffers x (A[2x128x64] + B[2x128x64]) bf16.
// Buffer byte map: A0=0, A1=16384, B0=32768, B1=49152.  buf1 base = 65536.
// EXACT round-2 reproduction (best-measured GEMM: 970us, MfmaUtil 51.5,
// 0 bank conflicts) including the original XCD swizzle.
__global__ __launch_bounds__(512, 2) void palett_gemm256(
    const unsigned short* __restrict__ A,   // [TOKENS][IN_F] bf16
    const unsigned short* __restrict__ B,   // [OUT_F][IN_F] bf16
    const float* __restrict__ bias,
    float* __restrict__ out)
{
    __shared__ __align__(16) char sm[131072];

    const int t    = threadIdx.x;
    const int w    = t >> 6;       // wave 0..7
    const int l    = t & 63;
    const int quad = l >> 4;
    const int r16  = l & 15;
    const int wr   = w >> 2;       // wave M row   (0..1) -> 128 rows
    const int wc   = w & 3;        // wave N col   (0..3) -> 64 cols

    // T1: XCD-aware bijective block swizzle (nwg=2048, 2048%8==0)
    const int orig = blockIdx.y * gridDim.x + blockIdx.x;   // 0..2047
    const int swzb = (orig & 7) * 256 + (orig >> 3);
    const int n0   = (swzb & 63) << 8;
    const int m0   = (swzb >> 6) << 8;

    // staging source (pre-swizzled): lane covers row srow (+8 for 2nd load),
    // 16B chunk at swizzled column ((l&7)^(l>>3))*8 elems.
    const int srow = w * 16 + (l >> 3);              // 0..127 within half
    const int scol = ((l & 7) ^ (l >> 3)) << 3;      // elems
    const unsigned short* pA = A + (size_t)(m0 + srow) * IN_F + scol;
    const unsigned short* pB = B + (size_t)(n0 + srow) * IN_F + scol;

    // ds_read byte-offset components (XOR-swizzled columns) — 0-conflict verified
    const int cswz  = (r16 & 7) << 4;
    const int col0  = (quad * 16) ^ cswz;            // kk=0
    const int col1  = (64 + quad * 16) ^ cswz;       // kk=1
    const int arow  = r16 * 128;
    const int abase = wr * 16384;                            // this wave's A half
    const int bbase = 32768 + (wc >> 1) * 16384 + (wc & 1) * 8192; // B half + sub

    f32x4  acc[8][4] = {};
    bf16x8 rA[4][2], rB0[2][2], rB1[2][2];

#define BARRIER() asm volatile("s_barrier" ::: "memory")

#define STAGE(P, HOFF, LOFF, KOFF) do {                                          \
    async_cp16((P) + (size_t)(HOFF) * IN_F + (KOFF), sm + (LOFF) + w * 2048);    \
    async_cp16((P) + (size_t)((HOFF) + 8) * IN_F + (KOFF),                       \
               sm + (LOFF) + w * 2048 + 1024);                                   \
} while (0)

#define READ_A(RB_, MH) do {                                                     \
    _Pragma("unroll")                                                            \
    for (int i_ = 0; i_ < 4; ++i_) {                                             \
        rA[i_][0] = *(const bf16x8*)(sm + (RB_) + abase + ((MH)*4 + i_)*2048 + arow + col0); \
        rA[i_][1] = *(const bf16x8*)(sm + (RB_) + abase + ((MH)*4 + i_)*2048 + arow + col1); \
    }                                                                            \
} while (0)

#define READ_B(DST, RB_, NH) do {                                                \
    _Pragma("unroll")                                                            \
    for (int j_ = 0; j_ < 2; ++j_) {                                             \
        DST[j_][0] = *(const bf16x8*)(sm + (RB_) + bbase + ((NH)*2 + j_)*2048 + arow + col0); \
        DST[j_][1] = *(const bf16x8*)(sm + (RB_) + bbase + ((NH)*2 + j_)*2048 + arow + col1); \
    }                                                                            \
} while (0)

#define MFMA_Q(MH, NH, RB) do {                                                  \
    _Pragma("unroll")                                                            \
    for (int i_ = 0; i_ < 4; ++i_) {                                             \
        _Pragma("unroll")                                                        \
        for (int j_ = 0; j_ < 2; ++j_) {                                         \
            acc[(MH)*4+i_][(NH)*2+j_] = __builtin_amdgcn_mfma_f32_16x16x32_bf16( \
                rA[i_][0], RB[j_][0], acc[(MH)*4+i_][(NH)*2+j_], 0, 0, 0);       \
            acc[(MH)*4+i_][(NH)*2+j_] = __builtin_amdgcn_mfma_f32_16x16x32_bf16( \
                rA[i_][1], RB[j_][1], acc[(MH)*4+i_][(NH)*2+j_], 0, 0, 0);       \
        }                                                                        \
    }                                                                            \
} while (0)

// KB_ = element k-offset of tile t+1 (B staging), KA_ = k-offset of tile t+2 (A staging)
#define TILE(RB_, WB_, KB_, KA_) do {                                            \
    /* P1: stage B(t+1); read A-lo,B0; Q00 */                                    \
    STAGE(pB, 0,   (WB_) + 32768, KB_);                                          \
    STAGE(pB, 128, (WB_) + 49152, KB_);                                          \
    READ_A(RB_, 0);                                                              \
    READ_B(rB0, RB_, 0);                                                         \
    __builtin_amdgcn_s_setprio(1);                                               \
    MFMA_Q(0, 0, rB0);                                                           \
    __builtin_amdgcn_s_setprio(0);                                               \
    BARRIER();                                                                   \
    /* P2: read B1; Q01; read A-hi; drain lgkm (R fully read by this wave) */    \
    READ_B(rB1, RB_, 1);                                                         \
    __builtin_amdgcn_s_setprio(1);                                               \
    MFMA_Q(0, 1, rB1);                                                           \
    __builtin_amdgcn_s_setprio(0);                                               \
    READ_A(RB_, 1);                                                              \
    asm volatile("s_waitcnt lgkmcnt(0)" ::: "memory");                           \
    BARRIER();   /* all waves' reads from RB_ complete -> RB_ writable */        \
    /* P3: stage A(t+2) into RB_; Q10 */                                         \
    STAGE(pA, 0,   (RB_) + 0,     KA_);                                          \
    STAGE(pA, 128, (RB_) + 16384, KA_);                                          \
    __builtin_amdgcn_s_setprio(1);                                               \
    MFMA_Q(1, 0, rB0);                                                           \
    __builtin_amdgcn_s_setprio(0);                                               \
    BARRIER();                                                                   \
    /* P4: Q11; gate (leaves only A(t+2) in flight); certify tile t+1 */         \
    __builtin_amdgcn_s_setprio(1);                                               \
    MFMA_Q(1, 1, rB1);                                                           \
    __builtin_amdgcn_s_setprio(0);                                               \
    asm volatile("s_waitcnt vmcnt(4)" ::: "memory");                             \
    BARRIER();                                                                   \
} while (0)

    // prologue: tile0 (all 4 half-tiles) + A half-tiles of tile1 ("P3(-1)")
    STAGE(pA, 0,   0,             0);    // A-lo(0) -> buf0
    STAGE(pA, 128, 16384,         0);    // A-hi(0)
    STAGE(pB, 0,   32768,         0);    // B-lo(0)
    STAGE(pB, 128, 49152,         0);    // B-hi(0)
    STAGE(pA, 0,   65536 + 0,     64);   // A-lo(1) -> buf1
    STAGE(pA, 128, 65536 + 16384, 64);   // A-hi(1)
    asm volatile("s_waitcnt vmcnt(4)" ::: "memory");  // tile0 landed, A(1) in flight
    BARRIER();

#pragma unroll 1
    for (int it = 0; it < 32; ++it) {
        const int tt = 2 * it;
        const int kB0 = ((tt + 1) & 63) * 64;   // B of tile tt+1
        const int kA0 = ((tt + 2) & 63) * 64;   // A of tile tt+2
        const int kB1 = ((tt + 2) & 63) * 64;   // B of tile tt+2
        const int kA1 = ((tt + 3) & 63) * 64;   // A of tile tt+3
        TILE(0,     65536, kB0, kA0);
        TILE(65536, 0,     kB1, kA1);
    }
    asm volatile("s_waitcnt vmcnt(0)" ::: "memory"); // drain dangling prefetch

#undef TILE
#undef MFMA_Q
#undef READ_B
#undef READ_A
#undef STAGE
#undef BARRIER

    // epilogue: C/D layout row = quad*4 + v, col = r16
    float bj[4];
#pragma unroll
    for (int j = 0; j < 4; ++j) bj[j] = bias[n0 + wc * 64 + j * 16 + r16];

#pragma unroll
    for (int mf = 0; mf < 8; ++mf) {
        const int mrow = m0 + wr * 128 + mf * 16 + quad * 4;
#pragma unroll
        for (int nf = 0; nf < 4; ++nf) {
            const int n = n0 + wc * 64 + nf * 16 + r16;
#pragma unroll
            for (int v = 0; v < 4; ++v)
                out[(size_t)(mrow + v) * OUT_F + n] = acc[mf][nf][v] + bj[nf];
        }
    }
}

// ---------------- fused fallback (only if workspace too small) ----------------
__global__ __launch_bounds__(256) void palett_gemm_fused(
    const float* __restrict__ Af,             // [M][K] fp32
    const int* __restrict__ Widx,             // [N][K] int32
    const float* __restrict__ lut,
    const float* __restrict__ bias,
    float* __restrict__ out)
{
    __shared__ __align__(16) unsigned short smA[128 * 32];
    __shared__ __align__(16) unsigned short smB[128 * 32];
    __shared__ float slut[256];

    const int t    = threadIdx.x;
    const int w    = t >> 6;
    const int l    = t & 63;
    const int quad = l >> 4;
    const int r16  = l & 15;
    const int wr   = w >> 1;
    const int wc   = w & 1;

    const int m0 = blockIdx.y * 128;
    const int n0 = blockIdx.x * 128;

    const int g0  = t * 8;
    const int row = g0 >> 5;
    const int col = g0 & 31;

    char* const smA_c = (char*)smA;
    char* const smB_c = (char*)smB;

    slut[t] = lut[t];
    __syncthreads();

    uint32_t aoff[4], boff[4];
#pragma unroll
    for (int i = 0; i < 4; ++i) {
        aoff[i] = (uint32_t)(((wr * 64 + i * 16 + r16) * 32 + quad * 8) * 2);
        boff[i] = (uint32_t)(((wc * 64 + i * 16 + r16) * 32 + quad * 8) * 2);
    }

    f32x4 acc[4][4] = {};

    const float* af0 = Af + (size_t)(m0 + row) * IN_F + col;
    const float* af1 = Af + (size_t)(m0 + row + 64) * IN_F + col;
    const int*   wi0 = Widx + (size_t)(n0 + row) * IN_F + col;
    const int*   wi1 = Widx + (size_t)(n0 + row + 64) * IN_F + col;

    for (int k0 = 0; k0 < IN_F; k0 += 32) {
        float4 x0 = *(const float4*)(af0 + k0);
        float4 x1 = *(const float4*)(af0 + k0 + 4);
        uint4 p;
        p.x = pack_bf16x2(x0.x, x0.y); p.y = pack_bf16x2(x0.z, x0.w);
        p.z = pack_bf16x2(x1.x, x1.y); p.w = pack_bf16x2(x1.z, x1.w);
        *(uint4*)(smA_c + t * 16) = p;
        x0 = *(const float4*)(af1 + k0);
        x1 = *(const float4*)(af1 + k0 + 4);
        p.x = pack_bf16x2(x0.x, x0.y); p.y = pack_bf16x2(x0.z, x0.w);
        p.z = pack_bf16x2(x1.x, x1.y); p.w = pack_bf16x2(x1.z, x1.w);
        *(uint4*)(smA_c + 4096 + t * 16) = p;

        int4 j0 = *(const int4*)(wi0 + k0);
        int4 j1 = *(const int4*)(wi0 + k0 + 4);
        p.x = pack_bf16x2(slut[j0.x], slut[j0.y]);
        p.y = pack_bf16x2(slut[j0.z], slut[j0.w]);
        p.z = pack_bf16x2(slut[j1.x], slut[j1.y]);
        p.w = pack_bf16x2(slut[j1.z], slut[j1.w]);
        *(uint4*)(smB_c + t * 16) = p;
        j0 = *(const int4*)(wi1 + k0);
        j1 = *(const int4*)(wi1 + k0 + 4);
        p.x = pack_bf16x2(slut[j0.x], slut[j0.y]);
        p.y = pack_bf16x2(slut[j0.z], slut[j0.w]);
        p.z = pack_bf16x2(slut[j1.x], slut[j1.y]);
        p.w = pack_bf16x2(slut[j1.z], slut[j1.w]);
        *(uint4*)(smB_c + 4096 + t * 16) = p;
        __syncthreads();

        bf16x8 afr[4], bfr[4];
#pragma unroll
        for (int i = 0; i < 4; ++i) afr[i] = *(const bf16x8*)(smA_c + aoff[i]);
#pragma unroll
        for (int j = 0; j < 4; ++j) bfr[j] = *(const bf16x8*)(smB_c + boff[j]);
#pragma unroll
        for (int i = 0; i < 4; ++i)
#pragma unroll
            for (int j = 0; j < 4; ++j)
                acc[i][j] = __builtin_amdgcn_mfma_f32_16x16x32_bf16(
                    afr[i], bfr[j], acc[i][j], 0, 0, 0);
        __syncthreads();
    }

    float bj[4];
#pragma unroll
    for (int j = 0; j < 4; ++j) bj[j] = bias[n0 + wc * 64 + j * 16 + r16];

#pragma unroll
    for (int i = 0; i < 4; ++i) {
        const int mbase = m0 + wr * 64 + i * 16 + quad * 4;
#pragma unroll
        for (int j = 0; j < 4; ++j) {
            const int n = n0 + wc * 64 + j * 16 + r16;
#pragma unroll
            for (int v = 0; v < 4; ++v) {
                out[(size_t)(mbase + v) * OUT_F + n] = acc[i][j][v] + bj[j];
            }
        }
    }
}

extern "C" void kernel_launch(void* const* d_in, const int* in_sizes, int n_in,
                              void* d_out, int out_size, void* d_ws, size_t ws_size,
                              hipStream_t stream) {
    const float* input = (const float*)d_in[0];   // [8192][4096] fp32
    const int*   widx  = (const int*)d_in[1];     // [16384][4096] int32
    const float* lut   = (const float*)d_in[2];   // [256] fp32
    const float* bias  = (const float*)d_in[3];   // [16384] fp32
    float* out = (float*)d_out;                   // [8192][16384] fp32

    const size_t aBytes = (size_t)TOKENS * IN_F * sizeof(unsigned short); //  64 MB
    const size_t bBytes = (size_t)OUT_F  * IN_F * sizeof(unsigned short); // 128 MB

    if (ws_size >= aBytes + bBytes) {
        unsigned short* wsA = (unsigned short*)d_ws;
        unsigned short* wsB = (unsigned short*)((char*)d_ws + aBytes);
        const int nA8  = (TOKENS * IN_F) / 8;   // 4194304
        const int nB16 = (OUT_F  * IN_F) / 16;  // 4194304
        cvt_input_kernel<<<(nA8 + 255) / 256, 256, 0, stream>>>(input, wsA, nA8);
        dequant_kernel<<<(nB16 + 255) / 256, 256, 0, stream>>>(widx, lut, wsB, nB16);
        dim3 grid2(OUT_F / 256, TOKENS / 256);    // (64, 32) = 2048 blocks
        palett_gemm256<<<grid2, 512, 0, stream>>>(wsA, wsB, bias, out);
    } else {
        dim3 grid(OUT_F / 128, TOKENS / 128);
        palett_gemm_fused<<<grid, 256, 0, stream>>>(input, widx, lut, bias, out);
    }
}